// Round 2
// baseline (107.803 us; speedup 1.0000x reference)
//
#include <hip/hip_runtime.h>

typedef unsigned int   u32;
typedef unsigned short u16;
typedef short bf16x8 __attribute__((ext_vector_type(8)));
typedef float f32x4  __attribute__((ext_vector_type(4)));

#define CIN   128
#define COUT  128
#define Hh    64
#define Ww    64
#define Bb    8
#define KPOS  9
#define NSS   9            // supersteps = kernel positions
#define PLANE 1288         // dwords per ks2-plane (1288 % 32 == 8 -> write stagger)
#define XT_ELEMS (Bb*Hh*Ww*CIN)   // 4,194,304 ushorts (8 MB)

// ---- helpers ----------------------------------------------------------
__device__ __forceinline__ float bflo(u32 u){ return __uint_as_float(u << 16); }
__device__ __forceinline__ float bfhi(u32 u){ return __uint_as_float(u & 0xffff0000u); }

__device__ __forceinline__ u32 packbf(float a, float b){
    u32 ua = __float_as_uint(a);
    u32 ub = __float_as_uint(b);
    ua += 0x7fffu + ((ua >> 16) & 1u);
    ub += 0x7fffu + ((ub >> 16) & 1u);
    return (ua >> 16) | (ub & 0xffff0000u);
}
__device__ __forceinline__ u16 tobf(float a){
    u32 ua = __float_as_uint(a);
    ua += 0x7fffu + ((ua >> 16) & 1u);
    return (u16)(ua >> 16);
}

// ---- kernel 1 (fused prep): blocks [0,4096) transpose x, [4096,4672) prep W
// transpose: x [B,CIN,H,W] f32 -> xT [B,H,W,CIN] bf16
// wprep:     weight [COUT,CIN,3,3] f32 -> Wt bf16 in A-fragment order
__global__ __launch_bounds__(256) void k_prep(const float* __restrict__ x,
                                              const float* __restrict__ w,
                                              u16* __restrict__ xT,
                                              u16* __restrict__ Wt){
    __shared__ float tile[32*33];
    int bi  = blockIdx.x;
    int tid = threadIdx.x;
    if (bi < 4096){
        int st = bi & 127, ct = (bi >> 7) & 3, b = bi >> 9;
        int sb = st * 32, cb = ct * 32;
        int i = tid >> 5, j = tid & 31;
        const float* xp = x + ((size_t)(b*CIN + cb) * 4096) + sb;
#pragma unroll
        for (int rr = 0; rr < 4; ++rr){
            int ci = i + rr*8;
            tile[ci*33 + j] = xp[(size_t)ci*4096 + j];
        }
        __syncthreads();
        int ii = tid >> 4, jj = tid & 15;
        u32* outp = (u32*)xT + ((size_t)b*4096 + sb)*64 + (cb >> 1) + jj;
#pragma unroll
        for (int rr = 0; rr < 2; ++rr){
            int sl = ii + rr*16;
            float v0 = tile[(2*jj  )*33 + sl];
            float v1 = tile[(2*jj+1)*33 + sl];
            outp[(size_t)sl*64] = packbf(v0, v1);
        }
    } else {
        int gid = (bi - 4096)*256 + tid;        // 0 .. 147455
        int jf   = gid & 7;
        int lane = (gid >> 3) & 63;
        int mt   = (gid >> 9) & 7;
        int kt   = gid >> 12;
        int m  = mt*16 + (lane & 15);
        int kk = (lane >> 4)*8 + jf;
        int ck = kt*32 + kk;
        int kpos = ck >> 7;
        int cin  = ck & 127;
        Wt[gid] = tobf(w[((size_t)m*128 + cin)*9 + kpos]);
    }
}

// ---- kernel 2: fused deformable-im2col producer + MFMA GEMM -----------
// grid 512: b = bi&7 (XCD-local batch), t = bi>>3 -> one ho row (64 pos).
// C-tile 128(cout) x 64(pos); 4 waves 2x2: wm -> 64 cout, wn -> 32 pos.
// SUPERSTEP = one kernel position (128 cin = 4 K-steps of 32):
//   - 1 barrier per superstep (9 total, was 36)
//   - 16 gather loads in flight per thread, issued a full superstep ahead
//   - offset loads prefetched one superstep ahead
// LDS: 2 x (4 planes x 64 pos x 32 bf16), plane stride 1288 dw staggers banks.
__global__ __launch_bounds__(256, 2)
void k_main(const float* __restrict__ off, const float* __restrict__ bias,
            const u16* __restrict__ xT, const u16* __restrict__ Wt,
            float* __restrict__ out){
    __shared__ u32 Vsm[2][4*PLANE];   // 41,216 B

    int tid = threadIdx.x;
    int bi  = blockIdx.x;
    int b   = bi & 7;
    int t   = bi >> 3;          // 0..63 == ho row
    int s0  = t * 64;

    // producer identity: 4 threads per position (32 cin each)
    int p  = tid >> 2, qt = tid & 3;
    int ho = t;
    int wo = p;
    const u16* xb_base = xT + (size_t)b * (Hh*Ww*CIN) + qt*32;

    // consumer identity
    int lane = tid & 63, wave = tid >> 6;
    int wm = wave >> 1, wn = wave & 1;
    int quad = lane >> 4, l16 = lane & 15;

    f32x4 acc[4][2];
#pragma unroll
    for (int i = 0; i < 4; ++i)
#pragma unroll
        for (int j = 0; j < 2; ++j) acc[i][j] = {0.f, 0.f, 0.f, 0.f};

    int   aa[4];
    float wt[4];
    float dyr, dxr;
    uint4 q[16];
    uint4 araw[2][4];

    // --- producer helpers ---
    auto off_load = [&](int kpos){
        size_t ob = ((size_t)(b*18 + 2*kpos))*4096 + (s0 + p);
        dyr = off[ob];
        dxr = off[ob + 4096];
    };
    auto state_calc = [&](int kpos){
        int kh = kpos / 3, kw = kpos - kh*3;
        float py = (float)(ho + kh - 1) + dyr;
        float px = (float)(wo + kw - 1) + dxr;
        float y0f = floorf(py), x0f = floorf(px);
        float ly = py - y0f, lx = px - x0f;
        int y0 = (int)y0f, x0 = (int)x0f;
        int y1 = y0 + 1,  x1 = x0 + 1;
        float my0 = (y0 >= 0 && y0 < Hh) ? 1.f : 0.f;
        float my1 = (y1 >= 0 && y1 < Hh) ? 1.f : 0.f;
        float mx0 = (x0 >= 0 && x0 < Ww) ? 1.f : 0.f;
        float mx1 = (x1 >= 0 && x1 < Ww) ? 1.f : 0.f;
        float omly = 1.f - ly, omlx = 1.f - lx;
        wt[0] = omly*omlx*my0*mx0;
        wt[1] = omly*lx  *my0*mx1;
        wt[2] = ly  *omlx*my1*mx0;
        wt[3] = ly  *lx  *my1*mx1;
        int cy0 = min(max(y0,0),Hh-1), cy1 = min(max(y1,0),Hh-1);
        int cx0 = min(max(x0,0),Ww-1), cx1 = min(max(x1,0),Ww-1);
        aa[0] = (cy0*Ww + cx0)*CIN;
        aa[1] = (cy0*Ww + cx1)*CIN;
        aa[2] = (cy1*Ww + cx0)*CIN;
        aa[3] = (cy1*Ww + cx1)*CIN;
    };
    auto gather = [&](){
#pragma unroll
        for (int c = 0; c < 4; ++c){
            const u16* s = xb_base + aa[c];
#pragma unroll
            for (int u = 0; u < 4; ++u)
                q[c*4 + u] = *(const uint4*)(s + u*8);
        }
    };
    auto blend_store = [&](int buf){
        u32* dst = &Vsm[buf][qt*PLANE + p*20];
#pragma unroll
        for (int u = 0; u < 4; ++u){
            u32 res[4];
#pragma unroll
            for (int d = 0; d < 4; ++d){
                float lo = 0.f, hi = 0.f;
#pragma unroll
                for (int c = 0; c < 4; ++c){
                    u32 v = ((const u32*)&q[c*4 + u])[d];
                    lo = fmaf(wt[c], bflo(v), lo);
                    hi = fmaf(wt[c], bfhi(v), hi);
                }
                res[d] = packbf(lo, hi);
            }
            *(uint4*)(dst + u*4) = *(const uint4*)res;
        }
    };
    auto loadA = [&](int ks, uint4 a[4]){
#pragma unroll
        for (int i = 0; i < 4; ++i)
            a[i] = *(const uint4*)(Wt + (size_t)(((ks*8 + wm*4 + i)*64 + lane))*8);
    };

    // --- prologue ---
    off_load(0);
    state_calc(0);
    gather();
    loadA(0, araw[0]);

    for (int kp = 0; kp < NSS; ++kp){
        bool have_nxt = (kp + 1 < NSS);
        if (have_nxt) off_load(kp + 1);     // off loads in flight over blend
        blend_store(kp & 1);                 // waits q(kp), writes V(kp)
        if (have_nxt){
            state_calc(kp + 1);
            gather();                        // q(kp+1) in flight over consume
        }
        __syncthreads();                     // V(kp) visible in buf kp&1

        // consume 4 K-steps from Vsm[kp&1]
#pragma unroll
        for (int ks2 = 0; ks2 < 4; ++ks2){
            int flat = kp*4 + ks2;
            if (flat < 35) loadA(flat + 1, araw[(ks2+1) & 1]);
            uint4 braw[2];
#pragma unroll
            for (int j = 0; j < 2; ++j)
                braw[j] = *(const uint4*)&Vsm[kp & 1][ks2*PLANE + ((wn*2 + j)*16 + l16)*20 + quad*4];
#pragma unroll
            for (int i = 0; i < 4; ++i){
                bf16x8 av = __builtin_bit_cast(bf16x8, araw[ks2 & 1][i]);
#pragma unroll
                for (int j = 0; j < 2; ++j){
                    bf16x8 bv = __builtin_bit_cast(bf16x8, braw[j]);
                    acc[i][j] = __builtin_amdgcn_mfma_f32_16x16x32_bf16(av, bv, acc[i][j], 0, 0, 0);
                }
            }
        }
    }

    // epilogue: D[row=quad*4+r][col=l16] + bias
#pragma unroll
    for (int i = 0; i < 4; ++i){
        int cout0 = (wm*4 + i)*16 + quad*4;
#pragma unroll
        for (int j = 0; j < 2; ++j){
            int pcol = (wn*2 + j)*16 + l16;
            size_t obase = ((size_t)(b*COUT + cout0))*4096 + (s0 + pcol);
#pragma unroll
            for (int r = 0; r < 4; ++r){
                out[obase + (size_t)r*4096] = acc[i][j][r] + bias[cout0 + r];
            }
        }
    }
}

// ---- launch -----------------------------------------------------------
extern "C" void kernel_launch(void* const* d_in, const int* in_sizes, int n_in,
                              void* d_out, int out_size, void* d_ws, size_t ws_size,
                              hipStream_t stream){
    const float* x    = (const float*)d_in[0];
    const float* off  = (const float*)d_in[1];
    const float* w    = (const float*)d_in[2];
    const float* bias = (const float*)d_in[3];
    float* out = (float*)d_out;

    u16* xT = (u16*)d_ws;            // 8 MB
    u16* Wt = xT + XT_ELEMS;         // 288 KB

    k_prep<<<dim3(4672), dim3(256), 0, stream>>>(x, w, xT, Wt);
    k_main<<<dim3(512),  dim3(256), 0, stream>>>(off, bias, xT, Wt, out);
}

// Round 3
// 100.782 us; speedup vs baseline: 1.0697x; 1.0697x over previous
//
#include <hip/hip_runtime.h>

typedef unsigned int   u32;
typedef unsigned short u16;
typedef _Float16 f16x8 __attribute__((ext_vector_type(8)));
typedef _Float16 f16x2 __attribute__((ext_vector_type(2)));
typedef float f32x4  __attribute__((ext_vector_type(4)));

#define CIN   128
#define COUT  128
#define Hh    64
#define Ww    64
#define Bb    8
#define KPOS  9
#define NSS   9            // supersteps = kernel positions
#define PLANE 1288         // dwords per k-plane (1288 % 32 == 8 -> write stagger)
#define XT_ELEMS (Bb*Hh*Ww*CIN)   // 4,194,304 ushorts (8 MB)

// ---- helpers ----------------------------------------------------------
__device__ __forceinline__ u32 packh(float a, float b){
    f16x2 t = { (_Float16)a, (_Float16)b };
    return __builtin_bit_cast(u32, t);
}
__device__ __forceinline__ u16 tof16(float a){
    _Float16 h = (_Float16)a;
    return __builtin_bit_cast(u16, h);
}

// ---- kernel 1 (fused prep): blocks [0,4096) transpose x, [4096,4672) prep W
// transpose: x [B,CIN,H,W] f32 -> xT [B,H,W,CIN] f16
// wprep:     weight [COUT,CIN,3,3] f32 -> Wt f16 in A-fragment order
__global__ __launch_bounds__(256) void k_prep(const float* __restrict__ x,
                                              const float* __restrict__ w,
                                              u16* __restrict__ xT,
                                              u16* __restrict__ Wt){
    __shared__ float tile[32*33];
    int bi  = blockIdx.x;
    int tid = threadIdx.x;
    if (bi < 4096){
        int st = bi & 127, ct = (bi >> 7) & 3, b = bi >> 9;
        int sb = st * 32, cb = ct * 32;
        int i = tid >> 5, j = tid & 31;
        const float* xp = x + ((size_t)(b*CIN + cb) * 4096) + sb;
#pragma unroll
        for (int rr = 0; rr < 4; ++rr){
            int ci = i + rr*8;
            tile[ci*33 + j] = xp[(size_t)ci*4096 + j];
        }
        __syncthreads();
        int ii = tid >> 4, jj = tid & 15;
        u32* outp = (u32*)xT + ((size_t)b*4096 + sb)*64 + (cb >> 1) + jj;
#pragma unroll
        for (int rr = 0; rr < 2; ++rr){
            int sl = ii + rr*16;
            float v0 = tile[(2*jj  )*33 + sl];
            float v1 = tile[(2*jj+1)*33 + sl];
            outp[(size_t)sl*64] = packh(v0, v1);
        }
    } else {
        int gid = (bi - 4096)*256 + tid;        // 0 .. 147455
        int jf   = gid & 7;
        int lane = (gid >> 3) & 63;
        int mt   = (gid >> 9) & 7;
        int kt   = gid >> 12;
        int m  = mt*16 + (lane & 15);
        int kk = (lane >> 4)*8 + jf;
        int ck = kt*32 + kk;
        int kpos = ck >> 7;
        int cin  = ck & 127;
        Wt[gid] = tof16(w[((size_t)m*128 + cin)*9 + kpos]);
    }
}

// ---- kernel 2: fused deformable-im2col producer + MFMA GEMM -----------
// grid 512: b = bi&7 (XCD-local batch), t = bi>>3 -> one ho row (64 pos).
// C-tile 128(cout) x 64(pos); 4 waves 2x2: wm -> 64 cout, wn -> 32 pos.
// SUPERSTEP = one kernel position (128 cin = 4 K-steps of 32):
//   - 1 barrier per superstep; gathers issued a full superstep ahead
//   - gather lane map: 4 threads/pos own a 16B COLUMN across the 4 cin
//     chunks -> every gather instruction is 64B-contiguous per 4-lane group
//   - V and W are fp16; bilinear blend via packed v_pk_fma_f16 (no unpack)
__global__ __launch_bounds__(256, 2)
void k_main(const float* __restrict__ off, const float* __restrict__ bias,
            const u16* __restrict__ xT, const u16* __restrict__ Wt,
            float* __restrict__ out){
    __shared__ u32 Vsm[2][4*PLANE];   // 41,216 B

    int tid = threadIdx.x;
    int bi  = blockIdx.x;
    int b   = bi & 7;
    int t   = bi >> 3;          // 0..63 == ho row
    int s0  = t * 64;

    // producer identity: 4 threads per position, each owns 16B column
    int p  = tid >> 2, sub = tid & 3;
    int ho = t;
    int wo = p;
    const u16* xb_base = xT + (size_t)b * (Hh*Ww*CIN) + sub*8;

    // consumer identity
    int lane = tid & 63, wave = tid >> 6;
    int wm = wave >> 1, wn = wave & 1;
    int quad = lane >> 4, l16 = lane & 15;

    f32x4 acc[4][2];
#pragma unroll
    for (int i = 0; i < 4; ++i)
#pragma unroll
        for (int j = 0; j < 2; ++j) acc[i][j] = {0.f, 0.f, 0.f, 0.f};

    int   aa[4];
    float wt[4];
    float dyr, dxr;
    uint4 q[4][4];        // [corner][cin-chunk]
    uint4 araw[2][4];

    // --- producer helpers ---
    auto off_load = [&](int kpos){
        size_t ob = ((size_t)(b*18 + 2*kpos))*4096 + (s0 + p);
        dyr = off[ob];
        dxr = off[ob + 4096];
    };
    auto state_calc = [&](int kpos){
        int kh = kpos / 3, kw = kpos - kh*3;
        float py = (float)(ho + kh - 1) + dyr;
        float px = (float)(wo + kw - 1) + dxr;
        float y0f = floorf(py), x0f = floorf(px);
        float ly = py - y0f, lx = px - x0f;
        int y0 = (int)y0f, x0 = (int)x0f;
        int y1 = y0 + 1,  x1 = x0 + 1;
        float my0 = (y0 >= 0 && y0 < Hh) ? 1.f : 0.f;
        float my1 = (y1 >= 0 && y1 < Hh) ? 1.f : 0.f;
        float mx0 = (x0 >= 0 && x0 < Ww) ? 1.f : 0.f;
        float mx1 = (x1 >= 0 && x1 < Ww) ? 1.f : 0.f;
        float omly = 1.f - ly, omlx = 1.f - lx;
        wt[0] = omly*omlx*my0*mx0;
        wt[1] = omly*lx  *my0*mx1;
        wt[2] = ly  *omlx*my1*mx0;
        wt[3] = ly  *lx  *my1*mx1;
        int cy0 = min(max(y0,0),Hh-1), cy1 = min(max(y1,0),Hh-1);
        int cx0 = min(max(x0,0),Ww-1), cx1 = min(max(x1,0),Ww-1);
        aa[0] = (cy0*Ww + cx0)*CIN;
        aa[1] = (cy0*Ww + cx1)*CIN;
        aa[2] = (cy1*Ww + cx0)*CIN;
        aa[3] = (cy1*Ww + cx1)*CIN;
    };
    auto gather = [&](){
#pragma unroll
        for (int c = 0; c < 4; ++c){
            const u16* s = xb_base + aa[c];
#pragma unroll
            for (int k = 0; k < 4; ++k)
                q[c][k] = *(const uint4*)(s + k*32);
        }
    };
    auto blend_store = [&](int buf){
        f16x2 w2[4];
#pragma unroll
        for (int c = 0; c < 4; ++c){
            _Float16 h = (_Float16)wt[c];
            w2[c] = (f16x2){h, h};
        }
        u32* dst = &Vsm[buf][p*20 + sub*4];
#pragma unroll
        for (int k = 0; k < 4; ++k){
            u32 res[4];
#pragma unroll
            for (int d = 0; d < 4; ++d){
                f16x2 a2 = {(_Float16)0.f, (_Float16)0.f};
#pragma unroll
                for (int c = 0; c < 4; ++c){
                    f16x2 v = __builtin_bit_cast(f16x2, ((const u32*)&q[c][k])[d]);
                    a2 = w2[c]*v + a2;    // v_pk_fma_f16
                }
                res[d] = __builtin_bit_cast(u32, a2);
            }
            *(uint4*)(dst + k*PLANE) = *(const uint4*)res;
        }
    };
    auto loadA = [&](int ks, uint4 a[4]){
#pragma unroll
        for (int i = 0; i < 4; ++i)
            a[i] = *(const uint4*)(Wt + (size_t)(((ks*8 + wm*4 + i)*64 + lane))*8);
    };

    // --- prologue ---
    off_load(0);
    state_calc(0);
    gather();
    loadA(0, araw[0]);

    for (int kp = 0; kp < NSS; ++kp){
        bool have_nxt = (kp + 1 < NSS);
        if (have_nxt) off_load(kp + 1);     // off loads in flight over blend
        blend_store(kp & 1);                 // waits q(kp), writes V(kp)
        if (have_nxt){
            state_calc(kp + 1);
            gather();                        // q(kp+1) in flight over consume
        }
        __syncthreads();                     // V(kp) visible in buf kp&1

        // consume 4 K-steps from Vsm[kp&1]
#pragma unroll
        for (int ks2 = 0; ks2 < 4; ++ks2){
            int flat = kp*4 + ks2;
            if (flat < 35) loadA(flat + 1, araw[(ks2+1) & 1]);
            uint4 braw[2];
#pragma unroll
            for (int j = 0; j < 2; ++j)
                braw[j] = *(const uint4*)&Vsm[kp & 1][ks2*PLANE + ((wn*2 + j)*16 + l16)*20 + quad*4];
#pragma unroll
            for (int i = 0; i < 4; ++i){
                f16x8 av = __builtin_bit_cast(f16x8, araw[ks2 & 1][i]);
#pragma unroll
                for (int j = 0; j < 2; ++j){
                    f16x8 bv = __builtin_bit_cast(f16x8, braw[j]);
                    acc[i][j] = __builtin_amdgcn_mfma_f32_16x16x32_f16(av, bv, acc[i][j], 0, 0, 0);
                }
            }
        }
    }

    // epilogue: D[row=quad*4+r][col=l16] + bias
#pragma unroll
    for (int i = 0; i < 4; ++i){
        int cout0 = (wm*4 + i)*16 + quad*4;
#pragma unroll
        for (int j = 0; j < 2; ++j){
            int pcol = (wn*2 + j)*16 + l16;
            size_t obase = ((size_t)(b*COUT + cout0))*4096 + (s0 + pcol);
#pragma unroll
            for (int r = 0; r < 4; ++r){
                out[obase + (size_t)r*4096] = acc[i][j][r] + bias[cout0 + r];
            }
        }
    }
}

// ---- launch -----------------------------------------------------------
extern "C" void kernel_launch(void* const* d_in, const int* in_sizes, int n_in,
                              void* d_out, int out_size, void* d_ws, size_t ws_size,
                              hipStream_t stream){
    const float* x    = (const float*)d_in[0];
    const float* off  = (const float*)d_in[1];
    const float* w    = (const float*)d_in[2];
    const float* bias = (const float*)d_in[3];
    float* out = (float*)d_out;

    u16* xT = (u16*)d_ws;            // 8 MB
    u16* Wt = xT + XT_ELEMS;         // 288 KB

    k_prep<<<dim3(4672), dim3(256), 0, stream>>>(x, w, xT, Wt);
    k_main<<<dim3(512),  dim3(256), 0, stream>>>(off, bias, xT, Wt, out);
}

// Round 4
// 98.565 us; speedup vs baseline: 1.0937x; 1.0225x over previous
//
#include <hip/hip_runtime.h>

typedef unsigned int   u32;
typedef unsigned short u16;
typedef _Float16 f16x8 __attribute__((ext_vector_type(8)));
typedef _Float16 f16x2 __attribute__((ext_vector_type(2)));
typedef float f32x4  __attribute__((ext_vector_type(4)));

#define CIN   128
#define COUT  128
#define Hh    64
#define Ww    64
#define Bb    8
#define KPOS  9
#define NSS   9            // supersteps = kernel positions
#define PLANE 1288         // dwords per k-plane (1288 % 32 == 8 -> write stagger)
#define XT_ELEMS (Bb*Hh*Ww*CIN)   // 4,194,304 ushorts (8 MB)

// ---- helpers ----------------------------------------------------------
__device__ __forceinline__ u32 packh(float a, float b){
    f16x2 t = { (_Float16)a, (_Float16)b };
    return __builtin_bit_cast(u32, t);
}
__device__ __forceinline__ u16 tof16(float a){
    _Float16 h = (_Float16)a;
    return __builtin_bit_cast(u16, h);
}

// ---- kernel 1 (fused prep): blocks [0,4096) transpose x, [4096,4672) prep W
// transpose: x [B,CIN,H,W] f32 -> xT [B,H,W,CIN] f16
// wprep:     weight [COUT,CIN,3,3] f32 -> Wt f16 in A-fragment order
__global__ __launch_bounds__(256) void k_prep(const float* __restrict__ x,
                                              const float* __restrict__ w,
                                              u16* __restrict__ xT,
                                              u16* __restrict__ Wt){
    __shared__ float tile[32*33];
    int bi  = blockIdx.x;
    int tid = threadIdx.x;
    if (bi < 4096){
        int st = bi & 127, ct = (bi >> 7) & 3, b = bi >> 9;
        int sb = st * 32, cb = ct * 32;
        int i = tid >> 5, j = tid & 31;
        const float* xp = x + ((size_t)(b*CIN + cb) * 4096) + sb;
#pragma unroll
        for (int rr = 0; rr < 4; ++rr){
            int ci = i + rr*8;
            tile[ci*33 + j] = xp[(size_t)ci*4096 + j];
        }
        __syncthreads();
        int ii = tid >> 4, jj = tid & 15;
        u32* outp = (u32*)xT + ((size_t)b*4096 + sb)*64 + (cb >> 1) + jj;
#pragma unroll
        for (int rr = 0; rr < 2; ++rr){
            int sl = ii + rr*16;
            float v0 = tile[(2*jj  )*33 + sl];
            float v1 = tile[(2*jj+1)*33 + sl];
            outp[(size_t)sl*64] = packh(v0, v1);
        }
    } else {
        int gid = (bi - 4096)*256 + tid;        // 0 .. 147455
        int jf   = gid & 7;
        int lane = (gid >> 3) & 63;
        int mt   = (gid >> 9) & 7;
        int kt   = gid >> 12;
        int m  = mt*16 + (lane & 15);
        int kk = (lane >> 4)*8 + jf;
        int ck = kt*32 + kk;
        int kpos = ck >> 7;
        int cin  = ck & 127;
        Wt[gid] = tof16(w[((size_t)m*128 + cin)*9 + kpos]);
    }
}

// ---- kernel 2: fused deformable-im2col producer + MFMA GEMM -----------
// grid 512: b = bi&7 (XCD-local batch), t = bi>>3 -> one ho row (64 pos).
// C-tile 128(cout) x 64(pos); 4 waves 2x2: wm -> 64 cout, wn -> 32 pos.
// SUPERSTEP = one kernel position (128 cin = 4 K-steps of 32):
//   - 1 barrier per superstep; gathers issued a full superstep ahead
//   - A-fragments prefetched TWO K-steps ahead (depth-4 static rotation):
//     ~310 cy/wave in flight > ~200 cy L2-hit latency, no vmcnt stall
//   - s_setprio(1) around each MFMA cluster (2 independent blocks/CU ->
//     phase diversity; favor the MFMA-issuing wave)
//   - V and W are fp16; bilinear blend via packed v_pk_fma_f16
__global__ __launch_bounds__(256, 2)
void k_main(const float* __restrict__ off, const float* __restrict__ bias,
            const u16* __restrict__ xT, const u16* __restrict__ Wt,
            float* __restrict__ out){
    __shared__ u32 Vsm[2][4*PLANE];   // 41,216 B

    int tid = threadIdx.x;
    int bi  = blockIdx.x;
    int b   = bi & 7;
    int t   = bi >> 3;          // 0..63 == ho row
    int s0  = t * 64;

    // producer identity: 4 threads per position, each owns 16B column
    int p  = tid >> 2, sub = tid & 3;
    int ho = t;
    int wo = p;
    const u16* xb_base = xT + (size_t)b * (Hh*Ww*CIN) + sub*8;

    // consumer identity
    int lane = tid & 63, wave = tid >> 6;
    int wm = wave >> 1, wn = wave & 1;
    int quad = lane >> 4, l16 = lane & 15;

    f32x4 acc[4][2];
#pragma unroll
    for (int i = 0; i < 4; ++i)
#pragma unroll
        for (int j = 0; j < 2; ++j) acc[i][j] = {0.f, 0.f, 0.f, 0.f};

    int   aa[4];
    float wt[4];
    float dyr, dxr;
    uint4 q[4][4];        // [corner][cin-chunk]
    uint4 araw[4][4];     // depth-4 A-fragment rotation, all-static indexing

    // --- producer helpers ---
    auto off_load = [&](int kpos){
        size_t ob = ((size_t)(b*18 + 2*kpos))*4096 + (s0 + p);
        dyr = off[ob];
        dxr = off[ob + 4096];
    };
    auto state_calc = [&](int kpos){
        int kh = kpos / 3, kw = kpos - kh*3;
        float py = (float)(ho + kh - 1) + dyr;
        float px = (float)(wo + kw - 1) + dxr;
        float y0f = floorf(py), x0f = floorf(px);
        float ly = py - y0f, lx = px - x0f;
        int y0 = (int)y0f, x0 = (int)x0f;
        int y1 = y0 + 1,  x1 = x0 + 1;
        float my0 = (y0 >= 0 && y0 < Hh) ? 1.f : 0.f;
        float my1 = (y1 >= 0 && y1 < Hh) ? 1.f : 0.f;
        float mx0 = (x0 >= 0 && x0 < Ww) ? 1.f : 0.f;
        float mx1 = (x1 >= 0 && x1 < Ww) ? 1.f : 0.f;
        float omly = 1.f - ly, omlx = 1.f - lx;
        wt[0] = omly*omlx*my0*mx0;
        wt[1] = omly*lx  *my0*mx1;
        wt[2] = ly  *omlx*my1*mx0;
        wt[3] = ly  *lx  *my1*mx1;
        int cy0 = min(max(y0,0),Hh-1), cy1 = min(max(y1,0),Hh-1);
        int cx0 = min(max(x0,0),Ww-1), cx1 = min(max(x1,0),Ww-1);
        aa[0] = (cy0*Ww + cx0)*CIN;
        aa[1] = (cy0*Ww + cx1)*CIN;
        aa[2] = (cy1*Ww + cx0)*CIN;
        aa[3] = (cy1*Ww + cx1)*CIN;
    };
    auto gather = [&](){
#pragma unroll
        for (int c = 0; c < 4; ++c){
            const u16* s = xb_base + aa[c];
#pragma unroll
            for (int k = 0; k < 4; ++k)
                q[c][k] = *(const uint4*)(s + k*32);
        }
    };
    auto blend_store = [&](int buf){
        f16x2 w2[4];
#pragma unroll
        for (int c = 0; c < 4; ++c){
            _Float16 h = (_Float16)wt[c];
            w2[c] = (f16x2){h, h};
        }
        u32* dst = &Vsm[buf][p*20 + sub*4];
#pragma unroll
        for (int k = 0; k < 4; ++k){
            u32 res[4];
#pragma unroll
            for (int d = 0; d < 4; ++d){
                f16x2 a2 = {(_Float16)0.f, (_Float16)0.f};
#pragma unroll
                for (int c = 0; c < 4; ++c){
                    f16x2 v = __builtin_bit_cast(f16x2, ((const u32*)&q[c][k])[d]);
                    a2 = w2[c]*v + a2;    // v_pk_fma_f16
                }
                res[d] = __builtin_bit_cast(u32, a2);
            }
            *(uint4*)(dst + k*PLANE) = *(const uint4*)res;
        }
    };
    auto loadA = [&](int ks, uint4 a[4]){
#pragma unroll
        for (int i = 0; i < 4; ++i)
            a[i] = *(const uint4*)(Wt + (size_t)(((ks*8 + wm*4 + i)*64 + lane))*8);
    };

    // --- prologue ---
    off_load(0);
    state_calc(0);
    gather();
    loadA(0, araw[0]);
    loadA(1, araw[1]);

    for (int kp = 0; kp < NSS; ++kp){
        bool have_nxt = (kp + 1 < NSS);
        if (have_nxt) off_load(kp + 1);     // off loads in flight over blend
        blend_store(kp & 1);                 // waits q(kp), writes V(kp)
        if (have_nxt){
            state_calc(kp + 1);
            gather();                        // q(kp+1) in flight over consume
        }
        __syncthreads();                     // V(kp) visible in buf kp&1

        // consume 4 K-steps from Vsm[kp&1]; flat = kp*4 + ks2, slot = ks2
#pragma unroll
        for (int ks2 = 0; ks2 < 4; ++ks2){
            int flat = kp*4 + ks2;
            if (flat + 2 < 36) loadA(flat + 2, araw[(ks2 + 2) & 3]);
            uint4 braw[2];
#pragma unroll
            for (int j = 0; j < 2; ++j)
                braw[j] = *(const uint4*)&Vsm[kp & 1][ks2*PLANE + ((wn*2 + j)*16 + l16)*20 + quad*4];
            __builtin_amdgcn_s_setprio(1);
#pragma unroll
            for (int i = 0; i < 4; ++i){
                f16x8 av = __builtin_bit_cast(f16x8, araw[ks2][i]);
#pragma unroll
                for (int j = 0; j < 2; ++j){
                    f16x8 bv = __builtin_bit_cast(f16x8, braw[j]);
                    acc[i][j] = __builtin_amdgcn_mfma_f32_16x16x32_f16(av, bv, acc[i][j], 0, 0, 0);
                }
            }
            __builtin_amdgcn_s_setprio(0);
        }
    }

    // epilogue: D[row=quad*4+r][col=l16] + bias
#pragma unroll
    for (int i = 0; i < 4; ++i){
        int cout0 = (wm*4 + i)*16 + quad*4;
#pragma unroll
        for (int j = 0; j < 2; ++j){
            int pcol = (wn*2 + j)*16 + l16;
            size_t obase = ((size_t)(b*COUT + cout0))*4096 + (s0 + pcol);
#pragma unroll
            for (int r = 0; r < 4; ++r){
                out[obase + (size_t)r*4096] = acc[i][j][r] + bias[cout0 + r];
            }
        }
    }
}

// ---- launch -----------------------------------------------------------
extern "C" void kernel_launch(void* const* d_in, const int* in_sizes, int n_in,
                              void* d_out, int out_size, void* d_ws, size_t ws_size,
                              hipStream_t stream){
    const float* x    = (const float*)d_in[0];
    const float* off  = (const float*)d_in[1];
    const float* w    = (const float*)d_in[2];
    const float* bias = (const float*)d_in[3];
    float* out = (float*)d_out;

    u16* xT = (u16*)d_ws;            // 8 MB
    u16* Wt = xT + XT_ELEMS;         // 288 KB

    k_prep<<<dim3(4672), dim3(256), 0, stream>>>(x, w, xT, Wt);
    k_main<<<dim3(512),  dim3(256), 0, stream>>>(off, bias, xT, Wt, out);
}